// Round 1
// baseline (11288.154 us; speedup 1.0000x reference)
//
#include <hip/hip_runtime.h>
#include <math.h>

#define N_NODES 100000
#define N_EDGES 1600000
#define NF 64
#define ORDER 8
#define NPB 64   // nodes per block in tail kernel

// x_cur = X*0.5 ; prop = x_cur ; x_next = 0
__global__ __launch_bounds__(256) void init_kernel(const float4* __restrict__ X,
    float4* __restrict__ xc, float4* __restrict__ xn, float4* __restrict__ prop, int n4) {
  int i = blockIdx.x * 256 + threadIdx.x;
  if (i >= n4) return;
  float4 v = X[i];
  v.x *= 0.5f; v.y *= 0.5f; v.z *= 0.5f; v.w *= 0.5f;
  xc[i] = v;
  prop[i] = v;
  xn[i] = make_float4(0.0f, 0.0f, 0.0f, 0.0f);
}

// 16 threads per edge, float4 per thread (64 feats). scatter-add to x_next.
__global__ __launch_bounds__(256) void edge_kernel(const float4* __restrict__ x,
    const int* __restrict__ src, const int* __restrict__ dst,
    const float* __restrict__ ew, float* __restrict__ xn) {
  int gt = blockIdx.x * 256 + threadIdx.x;
  int e = gt >> 4;
  int f4 = gt & 15;
  if (e >= N_EDGES) return;
  int s = src[e];
  int d = dst[e];
  float w = ew[e];
  float4 v = x[s * 16 + f4];
  float* o = xn + (size_t)d * NF + f4 * 4;
  atomicAdd(o + 0, v.x * w);
  atomicAdd(o + 1, v.y * w);
  atomicAdd(o + 2, v.z * w);
  atomicAdd(o + 3, v.w * w);
}

// prop += x_new ; zero the old-cur buffer (becomes next round's x_next)
__global__ __launch_bounds__(256) void accum_kernel(float4* __restrict__ prop,
    const float4* __restrict__ xnew, float4* __restrict__ xzero, int n4) {
  int i = blockIdx.x * 256 + threadIdx.x;
  if (i >= n4) return;
  float4 p = prop[i];
  float4 v = xnew[i];
  p.x += v.x; p.y += v.y; p.z += v.z; p.w += v.w;
  prop[i] = p;
  xzero[i] = make_float4(0.0f, 0.0f, 0.0f, 0.0f);
}

// Fused tail: Xp = normalize(prop/9); h = normalize(relu(Xp@W0+b0)); out = h@W1+b1
__global__ __launch_bounds__(256) void tail_kernel(
    const float* __restrict__ prop, const float* __restrict__ W0,
    const float* __restrict__ b0, const float* __restrict__ W1,
    const float* __restrict__ b1, float* __restrict__ out) {
  __shared__ float sX[NPB][65];   // padded vs bank conflicts
  __shared__ float sH[4][257];
  __shared__ float sInv[NPB];
  __shared__ float sRed[4];

  const int t = threadIdx.x;
  const int base = blockIdx.x * NPB;

  // load 64 nodes' prop rows (coalesced: contiguous 16 KB)
  for (int i = t; i < NPB * NF; i += 256) {
    int node = i >> 6, f = i & 63;
    int g = base + node;
    sX[node][f] = (g < N_NODES) ? prop[(size_t)g * NF + f] : 0.0f;
  }
  __syncthreads();

  // per-node row norm of Xp = prop/9 : scale = (1/9)/(1e-12 + ||prop||/9)
  if (t < NPB) {
    float s = 0.0f;
    #pragma unroll
    for (int k = 0; k < NF; ++k) { float v = sX[t][k]; s = fmaf(v, v, s); }
    float nrm = sqrtf(s) * (1.0f / 9.0f);
    sInv[t] = (1.0f / 9.0f) / (1e-12f + nrm);
  }
  __syncthreads();
  for (int i = t; i < NPB * NF; i += 256) {
    int node = i >> 6, f = i & 63;
    sX[node][f] *= sInv[node];
  }
  __syncthreads();

  const float myb0 = b0[t];

  for (int n4 = 0; n4 < NPB / 4; ++n4) {
    // GEMM1 + relu + row-norm for 4 nodes, h rows into LDS
    for (int j = 0; j < 4; ++j) {
      const int node = n4 * 4 + j;
      float acc = myb0;
      #pragma unroll
      for (int k = 0; k < NF; ++k)
        acc = fmaf(sX[node][k], W0[k * 256 + t], acc);  // W0 col read: coalesced, L2-hot
      acc = fmaxf(acc, 0.0f);
      float ss = acc * acc;
      #pragma unroll
      for (int m = 1; m < 64; m <<= 1) ss += __shfl_xor(ss, m, 64);
      if ((t & 63) == 0) sRed[t >> 6] = ss;
      __syncthreads();
      float tot = sRed[0] + sRed[1] + sRed[2] + sRed[3];
      float hinv = 1.0f / (1e-12f + sqrtf(tot));
      sH[j][t] = acc * hinv;
      __syncthreads();
    }
    // GEMM2: 4 nodes x 47 classes = 188 active threads
    if (t < 4 * 47) {
      const int j = t / 47, c = t % 47;
      float acc = b1[c];
      #pragma unroll 16
      for (int k = 0; k < 256; ++k)
        acc = fmaf(sH[j][k], W1[k * 47 + c], acc);     // coalesced over c
      const int g = base + n4 * 4 + j;
      if (g < N_NODES) out[(size_t)g * 47 + c] = acc;
    }
    __syncthreads();
  }
}

extern "C" void kernel_launch(void* const* d_in, const int* in_sizes, int n_in,
                              void* d_out, int out_size, void* d_ws, size_t ws_size,
                              hipStream_t stream) {
  (void)in_sizes; (void)n_in; (void)out_size; (void)ws_size;
  const float* X  = (const float*)d_in[0];
  const int*   src = (const int*)d_in[1];
  const int*   dst = (const int*)d_in[2];
  const float* ew = (const float*)d_in[3];
  const float* W0 = (const float*)d_in[4];
  const float* b0 = (const float*)d_in[5];
  const float* W1 = (const float*)d_in[6];
  const float* b1 = (const float*)d_in[7];
  float* out = (float*)d_out;

  const size_t nf = (size_t)N_NODES * NF;        // 6.4M floats
  float* bufA = (float*)d_ws;                    // 25.6 MB each
  float* bufB = bufA + nf;
  float* prop = bufB + nf;

  const int n4 = (int)(nf / 4);
  init_kernel<<<(n4 + 255) / 256, 256, 0, stream>>>(
      (const float4*)X, (float4*)bufA, (float4*)bufB, (float4*)prop, n4);

  float* xc = bufA;
  float* xn = bufB;
  for (int r = 0; r < ORDER; ++r) {
    const int ethreads = N_EDGES * 16;
    edge_kernel<<<(ethreads + 255) / 256, 256, 0, stream>>>(
        (const float4*)xc, src, dst, ew, xn);
    accum_kernel<<<(n4 + 255) / 256, 256, 0, stream>>>(
        (float4*)prop, (const float4*)xn, (float4*)xc, n4);
    float* tmp = xc; xc = xn; xn = tmp;
  }

  tail_kernel<<<(N_NODES + NPB - 1) / NPB, 256, 0, stream>>>(
      prop, W0, b0, W1, b1, out);
}

// Round 2
// 1348.052 us; speedup vs baseline: 8.3737x; 8.3737x over previous
//
#include <hip/hip_runtime.h>
#include <math.h>

#define N_NODES 100000
#define N_EDGES 1600000
#define NF 64
#define ORDER 8
#define NPB 64   // nodes per block in tail kernel

// ---------------- CSR build (once per launch) ----------------

__global__ __launch_bounds__(256) void zero_counts(int* __restrict__ c, int n) {
  int i = blockIdx.x * 256 + threadIdx.x;
  if (i < n) c[i] = 0;
}

__global__ __launch_bounds__(256) void hist_kernel(const int* __restrict__ dst,
                                                   int* __restrict__ counts) {
  int e = blockIdx.x * 256 + threadIdx.x;
  if (e < N_EDGES) atomicAdd(&counts[dst[e]], 1);
}

// single block, 1024 threads: exclusive scan of counts -> row_start (+cursor copy)
__global__ __launch_bounds__(1024) void scan_kernel(const int* __restrict__ counts,
                                                    int* __restrict__ row_start,
                                                    int* __restrict__ cursor) {
  __shared__ int sc[1024];
  const int t = threadIdx.x;
  const int CHUNK = (N_NODES + 1023) / 1024;   // 98
  const int beg = t * CHUNK;
  const int end = min(beg + CHUNK, N_NODES);
  int s = 0;
  for (int i = beg; i < end; ++i) s += counts[i];
  sc[t] = s;
  __syncthreads();
  for (int off = 1; off < 1024; off <<= 1) {
    int v = (t >= off) ? sc[t - off] : 0;
    __syncthreads();
    sc[t] += v;
    __syncthreads();
  }
  int run = sc[t] - s;   // exclusive prefix of this chunk
  for (int i = beg; i < end; ++i) {
    row_start[i] = run;
    cursor[i] = run;
    run += counts[i];
  }
  if (t == 1023) row_start[N_NODES] = run;
}

__global__ __launch_bounds__(256) void fill_kernel(const int* __restrict__ src,
    const int* __restrict__ dst, const float* __restrict__ ew,
    int* __restrict__ cursor, int2* __restrict__ adj) {
  int e = blockIdx.x * 256 + threadIdx.x;
  if (e >= N_EDGES) return;
  int d = dst[e];
  int pos = atomicAdd(&cursor[d], 1);
  adj[pos] = make_int2(src[e], __float_as_int(ew[e]));
}

// ---------------- propagation ----------------

// x_cur = X*0.5 ; prop = x_cur
__global__ __launch_bounds__(256) void init_kernel(const float4* __restrict__ X,
    float4* __restrict__ xc, float4* __restrict__ prop, int n4) {
  int i = blockIdx.x * 256 + threadIdx.x;
  if (i >= n4) return;
  float4 v = X[i];
  v.x *= 0.5f; v.y *= 0.5f; v.z *= 0.5f; v.w *= 0.5f;
  xc[i] = v;
  prop[i] = v;
}

// gather-sum per dst node: 16 lanes/node, float4/lane (64 feats).
// xn[d] = sum_{e in in(d)} x[src_e]*w_e ; prop[d] += xn[d]
__global__ __launch_bounds__(256) void spmm_csr(const float4* __restrict__ x,
    const int* __restrict__ row_start, const int2* __restrict__ adj,
    float4* __restrict__ xn, float4* __restrict__ prop) {
  const int node = blockIdx.x * 16 + (threadIdx.x >> 4);
  const int f4 = threadIdx.x & 15;
  if (node >= N_NODES) return;
  const int beg = row_start[node];
  const int end = row_start[node + 1];
  float4 acc = make_float4(0.f, 0.f, 0.f, 0.f);
  for (int p = beg; p < end; ++p) {
    int2 e = adj[p];                       // broadcast within 16-lane group
    float w = __int_as_float(e.y);
    float4 v = x[(size_t)e.x * 16 + f4];   // 256 B coalesced per group
    acc.x = fmaf(v.x, w, acc.x);
    acc.y = fmaf(v.y, w, acc.y);
    acc.z = fmaf(v.z, w, acc.z);
    acc.w = fmaf(v.w, w, acc.w);
  }
  const size_t o = (size_t)node * 16 + f4;
  xn[o] = acc;
  float4 pr = prop[o];
  pr.x += acc.x; pr.y += acc.y; pr.z += acc.z; pr.w += acc.w;
  prop[o] = pr;
}

// ---------------- fused tail ----------------
// Xp = normalize(prop/9); h = normalize(relu(Xp@W0+b0)); out = h@W1+b1
__global__ __launch_bounds__(256) void tail_kernel(
    const float* __restrict__ prop, const float* __restrict__ W0,
    const float* __restrict__ b0, const float* __restrict__ W1,
    const float* __restrict__ b1, float* __restrict__ out) {
  __shared__ float sX[NPB][65];
  __shared__ float sH[4][257];
  __shared__ float sInv[NPB];
  __shared__ float sRed[4];

  const int t = threadIdx.x;
  const int base = blockIdx.x * NPB;

  for (int i = t; i < NPB * NF; i += 256) {
    int node = i >> 6, f = i & 63;
    int g = base + node;
    sX[node][f] = (g < N_NODES) ? prop[(size_t)g * NF + f] : 0.0f;
  }
  __syncthreads();

  if (t < NPB) {
    float s = 0.0f;
    #pragma unroll
    for (int k = 0; k < NF; ++k) { float v = sX[t][k]; s = fmaf(v, v, s); }
    float nrm = sqrtf(s) * (1.0f / 9.0f);
    sInv[t] = (1.0f / 9.0f) / (1e-12f + nrm);
  }
  __syncthreads();
  for (int i = t; i < NPB * NF; i += 256) {
    int node = i >> 6, f = i & 63;
    sX[node][f] *= sInv[node];
  }
  __syncthreads();

  const float myb0 = b0[t];

  for (int n4 = 0; n4 < NPB / 4; ++n4) {
    for (int j = 0; j < 4; ++j) {
      const int node = n4 * 4 + j;
      float acc = myb0;
      #pragma unroll
      for (int k = 0; k < NF; ++k)
        acc = fmaf(sX[node][k], W0[k * 256 + t], acc);
      acc = fmaxf(acc, 0.0f);
      float ss = acc * acc;
      #pragma unroll
      for (int m = 1; m < 64; m <<= 1) ss += __shfl_xor(ss, m, 64);
      if ((t & 63) == 0) sRed[t >> 6] = ss;
      __syncthreads();
      float tot = sRed[0] + sRed[1] + sRed[2] + sRed[3];
      float hinv = 1.0f / (1e-12f + sqrtf(tot));
      sH[j][t] = acc * hinv;
      __syncthreads();
    }
    if (t < 4 * 47) {
      const int j = t / 47, c = t % 47;
      float acc = b1[c];
      #pragma unroll 16
      for (int k = 0; k < 256; ++k)
        acc = fmaf(sH[j][k], W1[k * 47 + c], acc);
      const int g = base + n4 * 4 + j;
      if (g < N_NODES) out[(size_t)g * 47 + c] = acc;
    }
    __syncthreads();
  }
}

extern "C" void kernel_launch(void* const* d_in, const int* in_sizes, int n_in,
                              void* d_out, int out_size, void* d_ws, size_t ws_size,
                              hipStream_t stream) {
  (void)in_sizes; (void)n_in; (void)out_size; (void)ws_size;
  const float* X  = (const float*)d_in[0];
  const int*   src = (const int*)d_in[1];
  const int*   dst = (const int*)d_in[2];
  const float* ew = (const float*)d_in[3];
  const float* W0 = (const float*)d_in[4];
  const float* b0 = (const float*)d_in[5];
  const float* W1 = (const float*)d_in[6];
  const float* b1 = (const float*)d_in[7];
  float* out = (float*)d_out;

  // workspace layout
  const size_t nf = (size_t)N_NODES * NF;        // 6.4M floats (25.6 MB)
  float* bufA = (float*)d_ws;
  float* bufB = bufA + nf;
  float* prop = bufB + nf;
  int*   counts    = (int*)(prop + nf);
  int*   row_start = counts + N_NODES;           // N_NODES+1
  int*   cursor    = row_start + (N_NODES + 1);
  int2*  adj       = (int2*)(((uintptr_t)(cursor + N_NODES) + 15) & ~(uintptr_t)15);

  const int eblocks = (N_EDGES + 255) / 256;     // 6250
  const int nblocks = (N_NODES + 255) / 256;     // 391

  // CSR build
  zero_counts<<<nblocks, 256, 0, stream>>>(counts, N_NODES);
  hist_kernel<<<eblocks, 256, 0, stream>>>(dst, counts);
  scan_kernel<<<1, 1024, 0, stream>>>(counts, row_start, cursor);
  fill_kernel<<<eblocks, 256, 0, stream>>>(src, dst, ew, cursor, adj);

  // init
  const int n4 = (int)(nf / 4);
  init_kernel<<<(n4 + 255) / 256, 256, 0, stream>>>(
      (const float4*)X, (float4*)bufA, (float4*)prop, n4);

  // 8 gather rounds
  float* xc = bufA;
  float* xn = bufB;
  for (int r = 0; r < ORDER; ++r) {
    spmm_csr<<<(N_NODES + 15) / 16, 256, 0, stream>>>(
        (const float4*)xc, row_start, adj, (float4*)xn, (float4*)prop);
    float* tmp = xc; xc = xn; xn = tmp;
  }

  tail_kernel<<<(N_NODES + NPB - 1) / NPB, 256, 0, stream>>>(
      prop, W0, b0, W1, b1, out);
}

// Round 3
// 1091.644 us; speedup vs baseline: 10.3405x; 1.2349x over previous
//
#include <hip/hip_runtime.h>
#include <math.h>

#define N_NODES 100000
#define N_EDGES 1600000
#define NF 64
#define ORDER 8

// ---------------- CSR build (once per launch) ----------------

__global__ __launch_bounds__(256) void zero_counts(int* __restrict__ c, int n) {
  int i = blockIdx.x * 256 + threadIdx.x;
  if (i < n) c[i] = 0;
}

__global__ __launch_bounds__(256) void hist_kernel(const int* __restrict__ dst,
                                                   int* __restrict__ counts) {
  int e = blockIdx.x * 256 + threadIdx.x;
  if (e < N_EDGES) atomicAdd(&counts[dst[e]], 1);
}

// single block, 1024 threads: exclusive scan of counts -> row_start (+cursor copy)
__global__ __launch_bounds__(1024) void scan_kernel(const int* __restrict__ counts,
                                                    int* __restrict__ row_start,
                                                    int* __restrict__ cursor) {
  __shared__ int sc[1024];
  const int t = threadIdx.x;
  const int CHUNK = (N_NODES + 1023) / 1024;   // 98
  const int beg = t * CHUNK;
  const int end = min(beg + CHUNK, N_NODES);
  int s = 0;
  for (int i = beg; i < end; ++i) s += counts[i];
  sc[t] = s;
  __syncthreads();
  for (int off = 1; off < 1024; off <<= 1) {
    int v = (t >= off) ? sc[t - off] : 0;
    __syncthreads();
    sc[t] += v;
    __syncthreads();
  }
  int run = sc[t] - s;
  for (int i = beg; i < end; ++i) {
    row_start[i] = run;
    cursor[i] = run;
    run += counts[i];
  }
  if (t == 1023) row_start[N_NODES] = run;
}

__global__ __launch_bounds__(256) void fill_kernel(const int* __restrict__ src,
    const int* __restrict__ dst, const float* __restrict__ ew,
    int* __restrict__ cursor, int2* __restrict__ adj) {
  int e = blockIdx.x * 256 + threadIdx.x;
  if (e >= N_EDGES) return;
  int d = dst[e];
  int pos = atomicAdd(&cursor[d], 1);
  adj[pos] = make_int2(src[e], __float_as_int(ew[e]));
}

// ---------------- propagation ----------------

__global__ __launch_bounds__(256) void init_kernel(const float4* __restrict__ X,
    float4* __restrict__ xc, float4* __restrict__ prop, int n4) {
  int i = blockIdx.x * 256 + threadIdx.x;
  if (i >= n4) return;
  float4 v = X[i];
  v.x *= 0.5f; v.y *= 0.5f; v.z *= 0.5f; v.w *= 0.5f;
  xc[i] = v;
  prop[i] = v;
}

// gather-sum per dst node: 16 lanes/node, float4/lane, 2-edge unroll for ILP.
__global__ __launch_bounds__(256) void spmm_csr(const float4* __restrict__ x,
    const int* __restrict__ row_start, const int2* __restrict__ adj,
    float4* __restrict__ xn, float4* __restrict__ prop) {
  const int node = blockIdx.x * 16 + (threadIdx.x >> 4);
  const int f4 = threadIdx.x & 15;
  if (node >= N_NODES) return;
  const int beg = row_start[node];
  const int end = row_start[node + 1];
  float4 acc0 = make_float4(0.f, 0.f, 0.f, 0.f);
  float4 acc1 = make_float4(0.f, 0.f, 0.f, 0.f);
  int p = beg;
  for (; p + 2 <= end; p += 2) {
    int2 e0 = adj[p];
    int2 e1 = adj[p + 1];
    float4 v0 = x[(size_t)e0.x * 16 + f4];
    float4 v1 = x[(size_t)e1.x * 16 + f4];
    float w0 = __int_as_float(e0.y);
    float w1 = __int_as_float(e1.y);
    acc0.x = fmaf(v0.x, w0, acc0.x); acc0.y = fmaf(v0.y, w0, acc0.y);
    acc0.z = fmaf(v0.z, w0, acc0.z); acc0.w = fmaf(v0.w, w0, acc0.w);
    acc1.x = fmaf(v1.x, w1, acc1.x); acc1.y = fmaf(v1.y, w1, acc1.y);
    acc1.z = fmaf(v1.z, w1, acc1.z); acc1.w = fmaf(v1.w, w1, acc1.w);
  }
  if (p < end) {
    int2 e0 = adj[p];
    float4 v0 = x[(size_t)e0.x * 16 + f4];
    float w0 = __int_as_float(e0.y);
    acc0.x = fmaf(v0.x, w0, acc0.x); acc0.y = fmaf(v0.y, w0, acc0.y);
    acc0.z = fmaf(v0.z, w0, acc0.z); acc0.w = fmaf(v0.w, w0, acc0.w);
  }
  acc0.x += acc1.x; acc0.y += acc1.y; acc0.z += acc1.z; acc0.w += acc1.w;
  const size_t o = (size_t)node * 16 + f4;
  xn[o] = acc0;
  float4 pr = prop[o];
  pr.x += acc0.x; pr.y += acc0.y; pr.z += acc0.z; pr.w += acc0.w;
  prop[o] = pr;
}

// ---------------- fused tail, register-blocked ----------------
// 32 nodes/block, 256 threads. Xp = normalize(prop/9);
// h = normalize(relu(Xp@W0+b0)); out = h@W1+b1.
__global__ __launch_bounds__(256) void tail_kernel(
    const float* __restrict__ prop, const float* __restrict__ W0,
    const float* __restrict__ b0, const float* __restrict__ W1,
    const float* __restrict__ b1, float* __restrict__ out) {
  __shared__ float sXT[64][33];    // [k][node], stride 33 -> conflict-free
  __shared__ float sHT[256][33];   // [k][node]
  __shared__ float sPart[32][33];  // [node][tc]
  __shared__ float sHinv[32];

  const int t = threadIdx.x;
  const int lane = t & 63;
  const int w = t >> 6;
  const int base = blockIdx.x * 32;   // 3125 * 32 == 100000 exactly

  // ---- load + Xp-normalize + transpose: wave handles one node per iter ----
  #pragma unroll
  for (int it = 0; it < 8; ++it) {
    const int nb = it * 4 + w;
    float v = prop[(size_t)(base + nb) * NF + lane];
    float ss = v * v;
    #pragma unroll
    for (int m = 1; m < 64; m <<= 1) ss += __shfl_xor(ss, m, 64);
    float nrm = sqrtf(ss) * (1.0f / 9.0f);
    float scale = (1.0f / 9.0f) / (1e-12f + nrm);
    sXT[lane][nb] = v * scale;
  }
  __syncthreads();

  // ---- GEMM1: thread = 8 cols (8*tc..) x 4 nodes (tn, tn+8, tn+16, tn+24) ----
  const int tc = t >> 3;   // 0..31
  const int tn = t & 7;    // 0..7
  const float4* W0v = (const float4*)W0;
  float4 b0a = ((const float4*)b0)[2 * tc];
  float4 b0b = ((const float4*)b0)[2 * tc + 1];
  float acc[4][8];
  #pragma unroll
  for (int j = 0; j < 4; ++j) {
    acc[j][0] = b0a.x; acc[j][1] = b0a.y; acc[j][2] = b0a.z; acc[j][3] = b0a.w;
    acc[j][4] = b0b.x; acc[j][5] = b0b.y; acc[j][6] = b0b.z; acc[j][7] = b0b.w;
  }
  #pragma unroll 2
  for (int k = 0; k < NF; ++k) {
    float4 wa = W0v[k * 64 + 2 * tc];
    float4 wb = W0v[k * 64 + 2 * tc + 1];
    float xs0 = sXT[k][tn];
    float xs1 = sXT[k][tn + 8];
    float xs2 = sXT[k][tn + 16];
    float xs3 = sXT[k][tn + 24];
    #pragma unroll
    for (int j = 0; j < 4; ++j) {
      float xs = (j == 0) ? xs0 : (j == 1) ? xs1 : (j == 2) ? xs2 : xs3;
      acc[j][0] = fmaf(xs, wa.x, acc[j][0]);
      acc[j][1] = fmaf(xs, wa.y, acc[j][1]);
      acc[j][2] = fmaf(xs, wa.z, acc[j][2]);
      acc[j][3] = fmaf(xs, wa.w, acc[j][3]);
      acc[j][4] = fmaf(xs, wb.x, acc[j][4]);
      acc[j][5] = fmaf(xs, wb.y, acc[j][5]);
      acc[j][6] = fmaf(xs, wb.z, acc[j][6]);
      acc[j][7] = fmaf(xs, wb.w, acc[j][7]);
    }
  }

  // relu + per-node partial sumsq
  #pragma unroll
  for (int j = 0; j < 4; ++j) {
    float part = 0.0f;
    #pragma unroll
    for (int i = 0; i < 8; ++i) {
      float a = fmaxf(acc[j][i], 0.0f);
      acc[j][i] = a;
      part = fmaf(a, a, part);
    }
    sPart[tn + 8 * j][tc] = part;
  }
  __syncthreads();

  if (t < 32) {
    float s = 0.0f;
    #pragma unroll
    for (int i = 0; i < 32; ++i) s += sPart[t][i];
    sHinv[t] = 1.0f / (1e-12f + sqrtf(s));
  }
  __syncthreads();

  // scale + store h transposed
  #pragma unroll
  for (int j = 0; j < 4; ++j) {
    float sc = sHinv[tn + 8 * j];
    #pragma unroll
    for (int i = 0; i < 8; ++i)
      sHT[8 * tc + i][tn + 8 * j] = acc[j][i] * sc;
  }
  __syncthreads();

  // ---- GEMM2: thread = 3 cols {tc2, tc2+16, tc2+32} x 2 nodes {tn2, tn2+16} ----
  const int tn2 = t & 15;
  const int tc2 = t >> 4;   // 0..15
  const bool c3 = (tc2 < 15);
  float a00 = b1[tc2],      a01 = b1[tc2 + 16], a02 = c3 ? b1[tc2 + 32] : 0.0f;
  float a10 = a00,          a11 = a01,          a12 = a02;
  #pragma unroll 4
  for (int k = 0; k < 256; ++k) {
    float h0 = sHT[k][tn2];
    float h1 = sHT[k][tn2 + 16];
    float w1a = W1[k * 47 + tc2];
    float w1b = W1[k * 47 + tc2 + 16];
    float w1c = c3 ? W1[k * 47 + tc2 + 32] : 0.0f;
    a00 = fmaf(h0, w1a, a00);
    a01 = fmaf(h0, w1b, a01);
    a02 = fmaf(h0, w1c, a02);
    a10 = fmaf(h1, w1a, a10);
    a11 = fmaf(h1, w1b, a11);
    a12 = fmaf(h1, w1c, a12);
  }
  {
    const size_t n0 = (size_t)(base + tn2) * 47;
    const size_t n1 = (size_t)(base + tn2 + 16) * 47;
    out[n0 + tc2] = a00;
    out[n0 + tc2 + 16] = a01;
    if (c3) out[n0 + tc2 + 32] = a02;
    out[n1 + tc2] = a10;
    out[n1 + tc2 + 16] = a11;
    if (c3) out[n1 + tc2 + 32] = a12;
  }
}

extern "C" void kernel_launch(void* const* d_in, const int* in_sizes, int n_in,
                              void* d_out, int out_size, void* d_ws, size_t ws_size,
                              hipStream_t stream) {
  (void)in_sizes; (void)n_in; (void)out_size; (void)ws_size;
  const float* X   = (const float*)d_in[0];
  const int*   src = (const int*)d_in[1];
  const int*   dst = (const int*)d_in[2];
  const float* ew  = (const float*)d_in[3];
  const float* W0  = (const float*)d_in[4];
  const float* b0  = (const float*)d_in[5];
  const float* W1  = (const float*)d_in[6];
  const float* b1  = (const float*)d_in[7];
  float* out = (float*)d_out;

  const size_t nf = (size_t)N_NODES * NF;
  float* bufA = (float*)d_ws;
  float* bufB = bufA + nf;
  float* prop = bufB + nf;
  int*   counts    = (int*)(prop + nf);
  int*   row_start = counts + N_NODES;
  int*   cursor    = row_start + (N_NODES + 1);
  int2*  adj       = (int2*)(((uintptr_t)(cursor + N_NODES) + 15) & ~(uintptr_t)15);

  const int eblocks = (N_EDGES + 255) / 256;
  const int nblocks = (N_NODES + 255) / 256;

  zero_counts<<<nblocks, 256, 0, stream>>>(counts, N_NODES);
  hist_kernel<<<eblocks, 256, 0, stream>>>(dst, counts);
  scan_kernel<<<1, 1024, 0, stream>>>(counts, row_start, cursor);
  fill_kernel<<<eblocks, 256, 0, stream>>>(src, dst, ew, cursor, adj);

  const int n4 = (int)(nf / 4);
  init_kernel<<<(n4 + 255) / 256, 256, 0, stream>>>(
      (const float4*)X, (float4*)bufA, (float4*)prop, n4);

  float* xc = bufA;
  float* xn = bufB;
  for (int r = 0; r < ORDER; ++r) {
    spmm_csr<<<(N_NODES + 15) / 16, 256, 0, stream>>>(
        (const float4*)xc, row_start, adj, (float4*)xn, (float4*)prop);
    float* tmp = xc; xc = xn; xn = tmp;
  }

  tail_kernel<<<N_NODES / 32, 256, 0, stream>>>(prop, W0, b0, W1, b1, out);
}